// Round 6
// baseline (132.811 us; speedup 1.0000x reference)
//
#include <hip/hip_runtime.h>
#include <hip/hip_bf16.h>

// bmm [16,256,512] @ [16,512,2048] -> [16,256,2048], fp32 in/out.
// R6: ZERO barriers in the K-loop. R1/R3/R5 all hit ~40us because every
// iteration convoyed all waves on vmcnt(0)+__syncthreads (burst-drain:
// 8 x ~5us chip-wide drains = 41us). Here: stage the whole 64x512 A-stripe
// in LDS once (64KB, XOR-swizzled for b128 banking), ONE barrier, then each
// wave streams B direct from global (16n x 4k = 4 cache lines/inst, optimal)
// with branch-free depth-1.5 register prefetch. Fine-grained vmcnt, no convoy.
// BM=64 BN=128, 4 waves = disjoint 32-col slices; wave tile 64x32 = 4x2 MFMAs.
// grid (16,4,16) = 1024 blocks, 2 blocks/CU (LDS-limited), 8 waves/CU.
#define NB 16
#define ND 256
#define NK 512
#define NT 2048
#define BM 64
#define BN 128

typedef __attribute__((ext_vector_type(8))) short short8;
typedef __attribute__((ext_vector_type(4))) float f32x4;

union S8U { short8 v; unsigned int u[4]; };
union BF2U { __hip_bfloat162 h; unsigned int u; };

__device__ inline unsigned int pack2bf(float a, float b) {
    BF2U c; c.h = __float22bfloat162_rn(make_float2(a, b));
    return c.u;
}

__global__ __launch_bounds__(256, 2)
void bmm_nobar(const float* __restrict__ x, const float* __restrict__ path,
               float* __restrict__ out) {
    const int n0 = blockIdx.x * BN;
    const int m0 = blockIdx.y * BM;
    const int b  = blockIdx.z;
    const int t    = threadIdx.x;
    const int lane = t & 63;
    const int wv   = t >> 6;
    const int wn   = wv * 32;        // wave n-slice (disjoint)
    const int q    = lane >> 4;
    const int lm   = lane & 15;

    // A-stripe in LDS: 64 rows x 512 k bf16 = 64KB. Row stride 512 (1024B).
    // Chunk c (8 shorts) of row r stored at chunk c ^ (r&7): b128 frag reads
    // get uniform bank-group distribution (the b128 floor, no pileup).
    __shared__ unsigned short As[BM * NK];

    const float* pgB = path + (size_t)b * NK * NT + n0 + wn;

    // ---- B prefetch for kt=0 BEFORE staging (independent of LDS; overlaps)
    float bv0[2][8], bv1[2][8];
#pragma unroll
    for (int nt = 0; nt < 2; ++nt)
#pragma unroll
        for (int j = 0; j < 8; ++j)
            bv0[nt][j] = pgB[(size_t)(q * 8 + j) * NT + nt * 16 + lm];

    // ---- stage A: 64x512 fp32 -> bf16, swizzled. 8192 float4 / 256 thr.
    const float* xg = x + ((size_t)b * ND + m0) * NK;
#pragma unroll
    for (int i = 0; i < 32; ++i) {
        int f   = t + i * 256;
        int row = f >> 7, c4 = f & 127;
        float4 v = *reinterpret_cast<const float4*>(xg + (size_t)row * NK + c4 * 4);
        uint2 p;
        p.x = pack2bf(v.x, v.y);
        p.y = pack2bf(v.z, v.w);
        int chunk = (c4 >> 1) ^ (row & 7);
        *reinterpret_cast<uint2*>(&As[row * NK + chunk * 8 + (c4 & 1) * 4]) = p;
    }
    __syncthreads();   // the ONLY barrier

    f32x4 acc[4][2];
#pragma unroll
    for (int i = 0; i < 4; ++i)
#pragma unroll
        for (int j = 0; j < 2; ++j)
            acc[i][j] = (f32x4){0.f, 0.f, 0.f, 0.f};

#define LOAD_B(dst, kt)                                                       \
    {                                                                         \
        const float* s_ = pgB + (size_t)((kt) * 32 + q * 8) * NT;             \
        _Pragma("unroll")                                                     \
        for (int nt = 0; nt < 2; ++nt)                                        \
            _Pragma("unroll")                                                 \
            for (int j = 0; j < 8; ++j)                                       \
                dst[nt][j] = s_[(size_t)j * NT + nt * 16 + lm];               \
    }

#define COMPUTE(kt, bv)                                                       \
    {                                                                         \
        short8 af[4], bfr[2];                                                 \
        _Pragma("unroll")                                                     \
        for (int mt = 0; mt < 4; ++mt) {                                      \
            int row = mt * 16 + lm;                                           \
            int chunk = ((kt) * 4 + q) ^ (lm & 7);                            \
            af[mt] = *reinterpret_cast<const short8*>(&As[row * NK + chunk * 8]); \
        }                                                                     \
        _Pragma("unroll")                                                     \
        for (int nt = 0; nt < 2; ++nt) {                                      \
            S8U s;                                                            \
            s.u[0] = pack2bf(bv[nt][0], bv[nt][1]);                           \
            s.u[1] = pack2bf(bv[nt][2], bv[nt][3]);                           \
            s.u[2] = pack2bf(bv[nt][4], bv[nt][5]);                           \
            s.u[3] = pack2bf(bv[nt][6], bv[nt][7]);                           \
            bfr[nt] = s.v;                                                    \
        }                                                                     \
        _Pragma("unroll")                                                     \
        for (int mt = 0; mt < 4; ++mt)                                        \
            _Pragma("unroll")                                                 \
            for (int nt = 0; nt < 2; ++nt)                                    \
                acc[mt][nt] = __builtin_amdgcn_mfma_f32_16x16x32_bf16(        \
                    af[mt], bfr[nt], acc[mt][nt], 0, 0, 0);                   \
    }

    // main loop: branch-free, 2 K-tiles per iteration, loads 1.5 tiles ahead
#pragma unroll 1
    for (int kt = 0; kt <= 12; kt += 2) {
        LOAD_B(bv1, kt + 1)
        COMPUTE(kt, bv0)
        LOAD_B(bv0, kt + 2)
        COMPUTE(kt + 1, bv1)
    }
    // tail: kt = 14, 15 (bv0 holds 14 from the last loop iteration)
    LOAD_B(bv1, 15)
    COMPUTE(14, bv0)
    COMPUTE(15, bv1)

    // epilogue: C/D layout col=lane&15, row=(lane>>4)*4+reg  [m89-verified]
    float* og = out + ((size_t)b * ND + m0) * NT + n0 + wn;
#pragma unroll
    for (int mt = 0; mt < 4; ++mt)
#pragma unroll
        for (int r = 0; r < 4; ++r) {
            int row = mt * 16 + q * 4 + r;
#pragma unroll
            for (int nt = 0; nt < 2; ++nt)
                og[(size_t)row * NT + nt * 16 + lm] = acc[mt][nt][r];
        }
}

extern "C" void kernel_launch(void* const* d_in, const int* in_sizes, int n_in,
                              void* d_out, int out_size, void* d_ws, size_t ws_size,
                              hipStream_t stream) {
    const float* x    = (const float*)d_in[0];   // [16, 256, 512]
    const float* path = (const float*)d_in[1];   // [16, 512, 2048]
    float* out        = (float*)d_out;           // [16, 256, 2048]
    dim3 grid(NT / BN, ND / BM, NB);             // (16, 4, 16) = 1024 blocks
    dim3 block(256);
    bmm_nobar<<<grid, block, 0, stream>>>(x, path, out);
}